// Round 6
// baseline (69.756 us; speedup 1.0000x reference)
//
#include <hip/hip_runtime.h>
#include <hip/hip_fp16.h>
#include <math.h>

#define E 8
#define DF 512
#define DE 128
#define H 8
#define S 64
#define GH 16
#define HD 16
#define B 2
#define NTOK 1024
#define QT 2          // query chunks of 64 per (b,e,h)
#define CMAX 256      // max group size supported (binomial max ~170 abs worst)
#define CT 128        // f-tile rows per staging pass
#define PADF 130      // fsh row stride (halfs)
#define PADW 56       // wall row stride (halfs), 112B: 16B-aligned rows

__device__ __forceinline__ float wave_sum(float v) {
    for (int m = 32; m; m >>= 1) v += __shfl_xor(v, m, 64);
    return v;
}

// ---- kernel 1: prep = lists (blk 0-7) + WfT transpose (8-23) + LN/gate f (24-151) ----
__global__ __launch_bounds__(256) void k_prep(
    const float* __restrict__ Wf, const float* __restrict__ fp,
    const float* __restrict__ x,
    const float* __restrict__ lnw, const float* __restrict__ lnb,
    const float* __restrict__ alpha,
    const float* __restrict__ Wg1, const float* __restrict__ bg1,
    const float* __restrict__ Wg2, const float* __restrict__ bg2,
    float* __restrict__ WfT, unsigned* __restrict__ cnt,
    unsigned* __restrict__ lst, float* __restrict__ fg) {
    __shared__ float sh[64][65];
    int bid = blockIdx.x, tid = threadIdx.x;
    if (bid < 8) {                        // ---- expert token lists ----
        if (tid >= 64) return;
        int e = bid, l = tid;
        unsigned c = 0;
        for (int base = 0; base < NTOK; base += 64) {
            int n = base + l;
            int ee = (int)(fp[n] * 8.0f);
            ee = ee > 7 ? 7 : ee;
            bool in = (ee == e);
            unsigned long long m = __ballot(in);
            unsigned pos = (unsigned)__popcll(m & ((1ull << l) - 1ull));
            if (in) lst[e * NTOK + c + pos] = (unsigned)n;
            c += (unsigned)__popcll(m);
        }
        if (l == 0) cnt[e] = c;
        return;
    }
    if (bid < 24) {                       // ---- Wf [512][128] -> WfT [128][512] ----
        int i = bid - 8, rt = i >> 1, ct2 = i & 1;
        const float* in = Wf + (size_t)rt * 64 * DE + ct2 * 64;
        float* out = WfT + (size_t)ct2 * 64 * DF + rt * 64;
        int c = tid & 63, r0 = tid >> 6;
        for (int r = r0; r < 64; r += 4) sh[r][c] = in[(size_t)r * DE + c];
        __syncthreads();
        for (int cc = r0; cc < 64; cc += 4)
            out[(size_t)cc * DF + c] = sh[c][cc];
        return;
    }
    // ---- f-compute: LN + gate, 4 tokens per wave ----
    float (*fw)[68] = (float(*)[68])sh;   // [wave*4+j][68]
    int wave = tid >> 6, lane = tid & 63;
    int t0 = (bid - 24) * 16 + wave * 4;  // token base (0..2047)
    int ej[4];
    for (int j = 0; j < 4; j++) {
        int t = t0 + j;
        int n = t & (NTOK - 1);
        const float* xr = x + (size_t)t * DF;
        float4 a  = *(const float4*)(xr + lane * 8);
        float4 b4 = *(const float4*)(xr + lane * 8 + 4);
        float s  = a.x + a.y + a.z + a.w + b4.x + b4.y + b4.z + b4.w;
        float ss = a.x*a.x + a.y*a.y + a.z*a.z + a.w*a.w
                 + b4.x*b4.x + b4.y*b4.y + b4.z*b4.z + b4.w*b4.w;
        s = wave_sum(s);
        ss = wave_sum(ss);
        float mu  = s * (1.0f / DF);
        float var = ss * (1.0f / DF) - mu * mu;
        float rs  = rsqrtf(var + 1e-5f);
        int e = (int)(fp[n] * 8.0f);
        e = e > 7 ? 7 : e;
        ej[j] = e;
        float f = (xr[e * 64 + lane] - mu) * rs * lnw[e * 64 + lane]
                + lnb[e * 64 + lane];
        fw[wave * 4 + j][lane] = f;
    }
    __syncthreads();
    // gate: lane = j*16 + h, 4 tokens in parallel
    int j = lane >> 4, h = lane & 15;
    int eg = ej[j];
    const float* wrow = Wg1 + ((size_t)eg * GH + h) * S;
    float g1 = bg1[eg * GH + h];
#pragma unroll 8
    for (int si = 0; si < S; si++) g1 += fw[wave * 4 + j][si] * wrow[si];
    g1 = 0.5f * g1 * (1.0f + erff(g1 * 0.70710678118654752f));
    float part = g1 * Wg2[eg * GH + h];
    part += __shfl_xor(part, 1, 64);
    part += __shfl_xor(part, 2, 64);
    part += __shfl_xor(part, 4, 64);
    part += __shfl_xor(part, 8, 64);
    float g2 = part + bg2[eg];
    float gate = 1.0f / (1.0f + __expf(-g2));
    float aw = 1.0f / (1.0f + __expf(-alpha[eg]));
    float gm = gate * aw + (1.0f - aw);
#pragma unroll
    for (int jj = 0; jj < 4; jj++) {
        float gmj = __shfl(gm, jj * 16, 64);
        fg[(size_t)(t0 + jj) * S + lane] = fw[wave * 4 + jj][lane] * gmj;
    }
}

// ---- kernel 2: fused QKV + block-diagonal flash attention ----
// block = (b,e,h,qt). LDS: fsh(fp16 f tile) + wall(fp16 W slices) -> K/V/Q in LDS
// -> 4-wave key-split online softmax -> F.
__global__ __launch_bounds__(256) void k_attn_fused(
    const float* __restrict__ Wq, const float* __restrict__ Wk,
    const float* __restrict__ Wv, const float* __restrict__ fg,
    const unsigned* __restrict__ cnt, const unsigned* __restrict__ lst,
    const float* __restrict__ temp, float* __restrict__ F) {
    __shared__ __align__(16) char smem[65280];
    __half (*fsh)[PADF] = (__half(*)[PADF])smem;                 // 16640 B
    __half (*wall)[PADW] = (__half(*)[PADW])(smem + 16640);      //  7168 B
    float (*qsh)[17]     = (float(*)[17])(smem + 23808);         //  8704 B  [2*64][17]
    float (*Ksh)[16]     = (float(*)[16])(smem + 32512);         // 16384 B  [256][16]
    float (*Vsh)[16]     = (float(*)[16])(smem + 48896);         // 16384 B  [256][16]
    float (*pmrg)[18]    = (float(*)[18])smem;                   // 18432 B  [4*64][18] alias

    int idx = blockIdx.x;                 // ((b*E+e)*H+h)*QT + qt
    int qt = idx & (QT - 1);
    int beh = idx / QT;
    int b = beh >> 6, e = (beh >> 3) & 7, h = beh & 7;
    int c = (int)cnt[e];
    if (c > CMAX) c = CMAX;
    if (qt * 64 >= c) return;
    const unsigned* L = lst + e * NTOK;
    int tid = threadIdx.x, wave = tid >> 6, lane = tid & 63;
    float inv_scale = 1.0f / (4.0f * fabsf(temp[0]));

    // stage per-head weight slices (fp16): wall[s][m*16+d], m=0:q 1:k 2:v
    for (int ix = tid; ix < 3 * HD * S; ix += 256) {
        int m = ix >> 10, r = ix & 1023, d = r >> 6, s = r & 63;
        const float* W = (m == 0) ? Wq : (m == 1) ? Wk : Wv;
        wall[s][m * 16 + d] =
            __float2half(W[((size_t)e * DE + h * HD + d) * S + s]);
    }

    int ntiles = (c + CT - 1) >> 7;
    int i2 = tid >> 1, dg = tid & 1;
    for (int ti = 0; ti < ntiles; ti++) {
        int tb = ti << 7;
        int cs = min(CT, c - tb);
        __syncthreads();      // fsh safe to overwrite; wall visible after this
        for (int ix = tid; ix < cs * 16; ix += 256) {
            int slot = ix >> 4, p4 = ix & 15;
            float4 v = ((const float4*)(fg +
                        (size_t)(b * NTOK + (int)L[tb + slot]) * S))[p4];
            fsh[p4 * 4 + 0][slot] = __float2half(v.x);
            fsh[p4 * 4 + 1][slot] = __float2half(v.y);
            fsh[p4 * 4 + 2][slot] = __float2half(v.z);
            fsh[p4 * 4 + 3][slot] = __float2half(v.w);
        }
        __syncthreads();
        if (i2 < cs) {
            bool doq = (i2 >> 6) == qt;   // wave-uniform
            float kk[8] = {0,0,0,0,0,0,0,0};
            float vv[8] = {0,0,0,0,0,0,0,0};
            float qq[8] = {0,0,0,0,0,0,0,0};
            for (int s = 0; s < S; s++) {
                float fv = __half2float(fsh[s][i2]);
                const __half* wr = wall[s] + dg * 8;
                union Uh { float4 f; __half2 hh[4]; };
                Uh uq, uk, uv;
                uq.f = *(const float4*)(wr);
                uk.f = *(const float4*)(wr + 16);
                uv.f = *(const float4*)(wr + 32);
#pragma unroll
                for (int p = 0; p < 4; p++) {
                    float2 w2;
                    w2 = __half22float2(uk.hh[p]);
                    kk[2*p] += fv * w2.x; kk[2*p+1] += fv * w2.y;
                    w2 = __half22float2(uv.hh[p]);
                    vv[2*p] += fv * w2.x; vv[2*p+1] += fv * w2.y;
                    if (doq) {
                        w2 = __half22float2(uq.hh[p]);
                        qq[2*p] += fv * w2.x; qq[2*p+1] += fv * w2.y;
                    }
                }
            }
            float* ko = Ksh[tb + i2];
            ((float4*)ko)[dg*2]   = make_float4(kk[0],kk[1],kk[2],kk[3]);
            ((float4*)ko)[dg*2+1] = make_float4(kk[4],kk[5],kk[6],kk[7]);
            float* vo = Vsh[tb + i2];
            ((float4*)vo)[dg*2]   = make_float4(vv[0],vv[1],vv[2],vv[3]);
            ((float4*)vo)[dg*2+1] = make_float4(vv[4],vv[5],vv[6],vv[7]);
            if (doq) {
                float* qo = qsh[(ti << 6) + (i2 & 63)];
#pragma unroll
                for (int p = 0; p < 8; p++) qo[dg * 8 + p] = qq[p];
            }
        }
    }
    __syncthreads();          // K/V/q complete

    int ck = (c + 3) >> 2;
    int k0 = wave * ck, k1 = min(c, k0 + ck);
    for (int qci = 0; qci < ntiles; qci++) {
        int qb = (qci << 7) + qt * 64;
        if (qb >= c) break;   // uniform
        float q[16];
        {
            const float* qp = qsh[(qci << 6) + lane];
#pragma unroll
            for (int d = 0; d < 16; d++) q[d] = qp[d] * inv_scale;
        }
        bool valid = (qb + lane) < c;
        float m = -INFINITY, l = 0.f;
        float acc[16];
#pragma unroll
        for (int d = 0; d < 16; d++) acc[d] = 0.f;
        for (int i = k0; i < k1; i++) {
            const float4* kr = (const float4*)Ksh[i];
            float4 ka = kr[0], kb = kr[1], kc = kr[2], kd = kr[3];
            float s = q[0]*ka.x + q[1]*ka.y + q[2]*ka.z + q[3]*ka.w
                    + q[4]*kb.x + q[5]*kb.y + q[6]*kb.z + q[7]*kb.w
                    + q[8]*kc.x + q[9]*kc.y + q[10]*kc.z + q[11]*kc.w
                    + q[12]*kd.x + q[13]*kd.y + q[14]*kd.z + q[15]*kd.w;
            if (__any(s - m > 8.0f)) {
                float mn = fmaxf(m, s);
                float r = __expf(m - mn);
                l *= r;
#pragma unroll
                for (int d = 0; d < 16; d++) acc[d] *= r;
                m = mn;
            }
            float p = __expf(s - m);
            l += p;
            const float4* vr = (const float4*)Vsh[i];
            float4 va = vr[0], vb = vr[1], vc = vr[2], vd = vr[3];
            acc[0] += p*va.x; acc[1] += p*va.y; acc[2] += p*va.z; acc[3] += p*va.w;
            acc[4] += p*vb.x; acc[5] += p*vb.y; acc[6] += p*vb.z; acc[7] += p*vb.w;
            acc[8] += p*vc.x; acc[9] += p*vc.y; acc[10]+= p*vc.z; acc[11]+= p*vc.w;
            acc[12]+= p*vd.x; acc[13]+= p*vd.y; acc[14]+= p*vd.z; acc[15]+= p*vd.w;
        }
        float* pp = pmrg[wave * 64 + lane];
        pp[0] = m; pp[1] = l;
#pragma unroll
        for (int d = 0; d < 16; d++) pp[2 + d] = acc[d];
        __syncthreads();
        if (wave == 0) {
            float M = pmrg[lane][0];
            M = fmaxf(M, pmrg[64 + lane][0]);
            M = fmaxf(M, pmrg[128 + lane][0]);
            M = fmaxf(M, pmrg[192 + lane][0]);
            float Lt = 0.f;
            float o[16];
#pragma unroll
            for (int d = 0; d < 16; d++) o[d] = 0.f;
#pragma unroll
            for (int w = 0; w < 4; w++) {
                const float* qq2 = pmrg[w * 64 + lane];
                float r = __expf(qq2[0] - M);
                Lt += qq2[1] * r;
#pragma unroll
                for (int d = 0; d < 16; d++) o[d] += qq2[2 + d] * r;
            }
            if (valid) {
                int nq = (int)L[qb + lane];
                float il = 1.0f / Lt;
                float* op = F + (size_t)(b * NTOK + nq) * DE + h * HD;
#pragma unroll
                for (int d4 = 0; d4 < 4; d4++)
                    ((float4*)op)[d4] = make_float4(o[4*d4]*il, o[4*d4+1]*il,
                                                    o[4*d4+2]*il, o[4*d4+3]*il);
            }
        }
        __syncthreads();
    }
}

// ---- kernel 3: proj (coalesced WfT) + bias + residual, 8 tokens/block ----
__global__ __launch_bounds__(256) void k_proj(
    const float* __restrict__ x, const float* __restrict__ F,
    const float* __restrict__ WfT, const float* __restrict__ bf,
    float* __restrict__ out) {
    __shared__ float fr[8][DE];
    int t0 = blockIdx.x * 8;
    int tid = threadIdx.x;
    ((float4*)fr)[tid] = ((const float4*)(F + (size_t)t0 * DE))[tid];
    __syncthreads();
    float acc0[8], acc1[8];
    float b0 = bf[tid], b1 = bf[tid + 256];
#pragma unroll
    for (int tk = 0; tk < 8; tk++) { acc0[tk] = b0; acc1[tk] = b1; }
#pragma unroll 4
    for (int k = 0; k < DE; k++) {
        float w0 = WfT[(size_t)k * DF + tid];
        float w1 = WfT[(size_t)k * DF + tid + 256];
#pragma unroll
        for (int tk = 0; tk < 8; tk++) {
            float fv = fr[tk][k];
            acc0[tk] += fv * w0;
            acc1[tk] += fv * w1;
        }
    }
#pragma unroll
    for (int tk = 0; tk < 8; tk++) {
        size_t rb = (size_t)(t0 + tk) * DF;
        out[rb + tid]       = x[rb + tid]       + acc0[tk];
        out[rb + tid + 256] = x[rb + tid + 256] + acc1[tk];
    }
}

extern "C" void kernel_launch(void* const* d_in, const int* in_sizes, int n_in,
                              void* d_out, int out_size, void* d_ws, size_t ws_size,
                              hipStream_t stream) {
    (void)in_sizes; (void)n_in; (void)out_size; (void)ws_size;
    const float* x     = (const float*)d_in[0];
    const float* fp    = (const float*)d_in[1];
    const float* lnw   = (const float*)d_in[2];
    const float* lnb   = (const float*)d_in[3];
    const float* alpha = (const float*)d_in[4];
    const float* Wg1   = (const float*)d_in[5];
    const float* bg1   = (const float*)d_in[6];
    const float* Wg2   = (const float*)d_in[7];
    const float* bg2   = (const float*)d_in[8];
    const float* Wq    = (const float*)d_in[9];
    const float* Wk    = (const float*)d_in[10];
    const float* Wv    = (const float*)d_in[11];
    const float* temp  = (const float*)d_in[12];
    const float* Wf    = (const float*)d_in[13];
    const float* bf    = (const float*)d_in[14];
    float* out = (float*)d_out;

    char* ws = (char*)d_ws;
    unsigned* cnt = (unsigned*)ws;                     // 32 B
    unsigned* lst = (unsigned*)(ws + 1024);            // 32 KB
    float* fg  = (float*)(ws + 65536);                 // 512 KB: [B*NTOK][64]
    float* Fb  = fg + (size_t)B * NTOK * S;            // 1 MB:  [B*NTOK][DE]
    float* WfT = Fb + (size_t)B * NTOK * DE;           // 256 KB: [DE][DF]

    hipLaunchKernelGGL(k_prep, dim3(152), dim3(256), 0, stream,
                       Wf, fp, x, lnw, lnb, alpha, Wg1, bg1, Wg2, bg2,
                       WfT, cnt, lst, fg);
    hipLaunchKernelGGL(k_attn_fused, dim3(B * E * H * QT), dim3(256), 0, stream,
                       Wq, Wk, Wv, fg, cnt, lst, temp, Fb);
    hipLaunchKernelGGL(k_proj, dim3(B * NTOK / 8), dim3(256), 0, stream,
                       x, Fb, WfT, bf, out);
}

// Round 7
// 54.878 us; speedup vs baseline: 1.2711x; 1.2711x over previous
//
#include <hip/hip_runtime.h>
#include <math.h>

#define E 8
#define DF 512
#define DE 128
#define H 8
#define S 64
#define GH 16
#define HD 16
#define B 2
#define NTOK 1024
#define QT 2          // query chunks of 64 per (b,e,h) in k_attn
#define KMAX 192      // LDS-staged key capacity (mean c=128, sigma~10.6; >192 -> global tail)

__device__ __forceinline__ float wave_sum(float v) {
    for (int m = 32; m; m >>= 1) v += __shfl_xor(v, m, 64);
    return v;
}

// ---- kernel 1: prep ----
// blocks 0-7: expert lists | 8-23: WfT | 24-71: WqT/WkT/WvT | 72-199: LN+gate -> fg
__global__ __launch_bounds__(256) void k_prep(
    const float* __restrict__ Wq, const float* __restrict__ Wk,
    const float* __restrict__ Wv, const float* __restrict__ Wf,
    const float* __restrict__ fp, const float* __restrict__ x,
    const float* __restrict__ lnw, const float* __restrict__ lnb,
    const float* __restrict__ alpha,
    const float* __restrict__ Wg1, const float* __restrict__ bg1,
    const float* __restrict__ Wg2, const float* __restrict__ bg2,
    float* __restrict__ WfT, float* __restrict__ WqT, float* __restrict__ WkT,
    float* __restrict__ WvT, unsigned* __restrict__ cnt,
    unsigned* __restrict__ lst, float* __restrict__ fg) {
    __shared__ float sh[64][65];
    int bid = blockIdx.x, tid = threadIdx.x;
    if (bid < 8) {                        // ---- expert token lists ----
        if (tid >= 64) return;
        int e = bid, l = tid;
        unsigned c = 0;
        for (int base = 0; base < NTOK; base += 64) {
            int n = base + l;
            int ee = (int)(fp[n] * 8.0f);
            ee = ee > 7 ? 7 : ee;
            bool in = (ee == e);
            unsigned long long m = __ballot(in);
            unsigned pos = (unsigned)__popcll(m & ((1ull << l) - 1ull));
            if (in) lst[e * NTOK + c + pos] = (unsigned)n;
            c += (unsigned)__popcll(m);
        }
        if (l == 0) cnt[e] = c;
        return;
    }
    if (bid < 72) {                       // ---- transposes ----
        const float* in;
        float* out;
        int istride, ostride;
        if (bid < 24) {                   // Wf [512][128] -> WfT [128][512]
            int i = bid - 8, rt = i >> 1, ct2 = i & 1;
            in = Wf + (size_t)rt * 64 * DE + ct2 * 64;
            out = WfT + (size_t)ct2 * 64 * DF + rt * 64;
            istride = DE; ostride = DF;
        } else {                          // Wq/Wk/Wv [128][64]/expert -> [64][128]
            int bb = bid - 24;
            int m = bb >> 4, e = (bb >> 1) & 7, dt = bb & 1;
            const float* W = (m == 0) ? Wq : (m == 1) ? Wk : Wv;
            float* WT      = (m == 0) ? WqT : (m == 1) ? WkT : WvT;
            in = W + (size_t)e * DE * S + (size_t)dt * 64 * S;
            out = WT + (size_t)e * S * DE + dt * 64;
            istride = S; ostride = DE;
        }
        int c = tid & 63, r0 = tid >> 6;
        for (int r = r0; r < 64; r += 4) sh[r][c] = in[(size_t)r * istride + c];
        __syncthreads();
        for (int cc = r0; cc < 64; cc += 4)
            out[(size_t)cc * ostride + c] = sh[c][cc];
        return;
    }
    // ---- f-compute: LN + gate, 4 tokens per wave ----
    float (*fw)[68] = (float(*)[68])sh;   // [wave*4+j][68]
    int wave = tid >> 6, lane = tid & 63;
    int t0 = (bid - 72) * 16 + wave * 4;  // token base (0..2047)
    int ej[4];
    for (int j = 0; j < 4; j++) {
        int t = t0 + j;
        int n = t & (NTOK - 1);
        const float* xr = x + (size_t)t * DF;
        float4 a  = *(const float4*)(xr + lane * 8);
        float4 b4 = *(const float4*)(xr + lane * 8 + 4);
        float s  = a.x + a.y + a.z + a.w + b4.x + b4.y + b4.z + b4.w;
        float ss = a.x*a.x + a.y*a.y + a.z*a.z + a.w*a.w
                 + b4.x*b4.x + b4.y*b4.y + b4.z*b4.z + b4.w*b4.w;
        s = wave_sum(s);
        ss = wave_sum(ss);
        float mu  = s * (1.0f / DF);
        float var = ss * (1.0f / DF) - mu * mu;
        float rs  = rsqrtf(var + 1e-5f);
        int e = (int)(fp[n] * 8.0f);
        e = e > 7 ? 7 : e;
        ej[j] = e;
        float f = (xr[e * 64 + lane] - mu) * rs * lnw[e * 64 + lane]
                + lnb[e * 64 + lane];
        fw[wave * 4 + j][lane] = f;
    }
    __syncthreads();
    int j = lane >> 4, h = lane & 15;
    int eg = ej[j];
    const float* wrow = Wg1 + ((size_t)eg * GH + h) * S;
    float g1 = bg1[eg * GH + h];
#pragma unroll 8
    for (int si = 0; si < S; si++) g1 += fw[wave * 4 + j][si] * wrow[si];
    g1 = 0.5f * g1 * (1.0f + erff(g1 * 0.70710678118654752f));
    float part = g1 * Wg2[eg * GH + h];
    part += __shfl_xor(part, 1, 64);
    part += __shfl_xor(part, 2, 64);
    part += __shfl_xor(part, 4, 64);
    part += __shfl_xor(part, 8, 64);
    float g2 = part + bg2[eg];
    float gate = 1.0f / (1.0f + __expf(-g2));
    float aw = 1.0f / (1.0f + __expf(-alpha[eg]));
    float gm = gate * aw + (1.0f - aw);
#pragma unroll
    for (int jj = 0; jj < 4; jj++) {
        float gmj = __shfl(gm, jj * 16, 64);
        fg[(size_t)(t0 + jj) * S + lane] = fw[wave * 4 + jj][lane] * gmj;
    }
}

// ---- kernel 2: grouped QKV from fg (4 tokens/wave share one weight stream) ----
__global__ __launch_bounds__(256) void k_qkv(
    const float* __restrict__ fg,
    const float* __restrict__ WqT, const float* __restrict__ WkT,
    const float* __restrict__ WvT,
    const unsigned* __restrict__ cnt, const unsigned* __restrict__ lst,
    float* __restrict__ Q, float* __restrict__ K, float* __restrict__ V) {
    __shared__ float fsh[4][4][68];      // wave-private slabs
    int wave = threadIdx.x >> 6;
    int lane = threadIdx.x & 63;
    int bid = blockIdx.x;                // b*128 + e*16 + chunk
    int chunk = bid & 15;
    int e = (bid >> 4) & 7;
    int b = bid >> 7;
    int c = (int)cnt[e];
    if (chunk * 16 >= c) return;
    const unsigned* L = lst + e * NTOK;
    size_t wo = (size_t)e * S * DE;
    const float* Wqe = WqT + wo;
    const float* Wke = WkT + wo;
    const float* Wve = WvT + wo;
    int d2 = lane * 2;

    for (int it = 0; chunk * 16 + it * 256 < c; ++it) {
        int ib = it * 256 + chunk * 16 + wave * 4;
        int nj[4];
#pragma unroll
        for (int j = 0; j < 4; j++) {
            int ti = ib + j;
            int n = (int)L[ti < c ? ti : c - 1];
            nj[j] = n;
            fsh[wave][j][lane] = fg[(size_t)(b * NTOK + n) * S + lane];
        }
        // wave-private LDS; compiler inserts lgkmcnt before reads
        float2 qa[4], ka[4], va[4];
#pragma unroll
        for (int j = 0; j < 4; j++) { qa[j] = {0,0}; ka[j] = {0,0}; va[j] = {0,0}; }
#pragma unroll 4
        for (int si = 0; si < S; si++) {
            float2 wq = *(const float2*)(Wqe + (size_t)si * DE + d2);
            float2 wk = *(const float2*)(Wke + (size_t)si * DE + d2);
            float2 wv = *(const float2*)(Wve + (size_t)si * DE + d2);
#pragma unroll
            for (int j = 0; j < 4; j++) {
                float fv = fsh[wave][j][si];
                qa[j].x += fv * wq.x; qa[j].y += fv * wq.y;
                ka[j].x += fv * wk.x; ka[j].y += fv * wk.y;
                va[j].x += fv * wv.x; va[j].y += fv * wv.y;
            }
        }
#pragma unroll
        for (int j = 0; j < 4; j++) {
            if (ib + j < c) {
                size_t ob = (size_t)(b * NTOK + nj[j]) * DE + d2;
                *(float2*)(Q + ob) = qa[j];
                *(float2*)(K + ob) = ka[j];
                *(float2*)(V + ob) = va[j];
            }
        }
    }
}

// ---- kernel 3: block-diagonal flash attention, branchless 16-key chunks ----
__global__ __launch_bounds__(256) void k_attn(
    const float* __restrict__ Q, const float* __restrict__ K,
    const float* __restrict__ V, const unsigned* __restrict__ cnt,
    const unsigned* __restrict__ lst, const float* __restrict__ temp,
    float* __restrict__ F) {
    __shared__ float Ksh[KMAX][HD];       // 12 KB
    __shared__ float Vsh[KMAX][HD];       // 12 KB
    __shared__ float part[4][64][18];     // 18 KB
    int idx = blockIdx.x;                 // beh*QT + qt
    int qt = idx & (QT - 1);
    int beh = idx / QT;
    int b = beh >> 6, e = (beh >> 3) & 7, h = beh & 7;
    int c = (int)cnt[e];
    int qbase0 = qt * 64;
    if (qbase0 >= c) return;
    int cs = c < KMAX ? c : KMAX;
    const unsigned* L = lst + e * NTOK;
    int tid = threadIdx.x, wave = tid >> 6, lane = tid & 63;
    float inv_scale = 1.0f / (4.0f * fabsf(temp[0]));

    for (int j2 = tid; j2 < cs * 4; j2 += 256) {
        int i = j2 >> 2, comp = j2 & 3;
        int nk = (int)L[i];
        size_t rb = (size_t)(b * NTOK + nk) * DE + h * HD;
        ((float4*)Ksh[i])[comp] = ((const float4*)(K + rb))[comp];
        ((float4*)Vsh[i])[comp] = ((const float4*)(V + rb))[comp];
    }
    __syncthreads();

    int ck = (c + 3) >> 2;
    int k0 = wave * ck, k1 = min(c, k0 + ck);
    int kls = min(k1, cs);

    for (int qb = qbase0; qb < c; qb += QT * 64) {
        int qi = qb + lane;
        bool valid = qi < c;
        int nq = (int)L[valid ? qi : c - 1];
        const float* qp = Q + ((size_t)(b * NTOK + nq) * DE + h * HD);
        float q[16];
#pragma unroll
        for (int d4 = 0; d4 < 4; d4++) {
            float4 qv = ((const float4*)qp)[d4];
            q[4*d4] = qv.x * inv_scale; q[4*d4+1] = qv.y * inv_scale;
            q[4*d4+2] = qv.z * inv_scale; q[4*d4+3] = qv.w * inv_scale;
        }
        float m = -1e30f, l = 0.f;
        float acc[16];
#pragma unroll
        for (int d = 0; d < 16; d++) acc[d] = 0.f;

        for (int i0 = k0; i0 < kls; i0 += 16) {
            float sreg[16];
            float cmax = -1e30f;
#pragma unroll
            for (int j = 0; j < 16; j++) {
                int i = i0 + j;
                bool v = i < kls;
                int ii = v ? i : k0;
                const float4* kr = (const float4*)Ksh[ii];
                float4 ka = kr[0], kb = kr[1], kc = kr[2], kd = kr[3];
                float s = q[0]*ka.x + q[1]*ka.y + q[2]*ka.z + q[3]*ka.w
                        + q[4]*kb.x + q[5]*kb.y + q[6]*kb.z + q[7]*kb.w
                        + q[8]*kc.x + q[9]*kc.y + q[10]*kc.z + q[11]*kc.w
                        + q[12]*kd.x + q[13]*kd.y + q[14]*kd.z + q[15]*kd.w;
                s = v ? s : -1e30f;
                sreg[j] = s;
                cmax = fmaxf(cmax, s);
            }
            float mn = fmaxf(m, cmax);
            float r = __expf(m - mn);
            l *= r;
#pragma unroll
            for (int d = 0; d < 16; d++) acc[d] *= r;
            m = mn;
#pragma unroll
            for (int j = 0; j < 16; j++) {
                int i = i0 + j;
                bool v = i < kls;
                int ii = v ? i : k0;
                float p = __expf(sreg[j] - m);   // 0 for invalid slots
                l += p;
                const float4* vr = (const float4*)Vsh[ii];
                float4 va = vr[0], vb = vr[1], vc = vr[2], vd = vr[3];
                acc[0] += p*va.x; acc[1] += p*va.y; acc[2] += p*va.z; acc[3] += p*va.w;
                acc[4] += p*vb.x; acc[5] += p*vb.y; acc[6] += p*vb.z; acc[7] += p*vb.w;
                acc[8] += p*vc.x; acc[9] += p*vc.y; acc[10]+= p*vc.z; acc[11]+= p*vc.w;
                acc[12]+= p*vd.x; acc[13]+= p*vd.y; acc[14]+= p*vd.z; acc[15]+= p*vd.w;
            }
        }
        for (int i = max(k0, cs); i < k1; i++) {   // global tail (never taken normally)
            int nk = (int)L[i];
            size_t rb = (size_t)(b * NTOK + nk) * DE + h * HD;
            const float* kp = K + rb;
            float s = 0.f;
            for (int dd = 0; dd < 16; dd++) s += q[dd] * kp[dd];
            float mn = fmaxf(m, s);
            float r = __expf(m - mn);
            l *= r;
#pragma unroll
            for (int d = 0; d < 16; d++) acc[d] *= r;
            m = mn;
            float p = __expf(s - m);
            l += p;
            const float* vp = V + rb;
#pragma unroll
            for (int d = 0; d < 16; d++) acc[d] += p * vp[d];
        }

        float* pp = part[wave][lane];
        pp[0] = m; pp[1] = l;
#pragma unroll
        for (int d = 0; d < 16; d++) pp[2 + d] = acc[d];
        __syncthreads();

        if (wave == 0) {
            float M = part[0][lane][0];
            M = fmaxf(M, part[1][lane][0]);
            M = fmaxf(M, part[2][lane][0]);
            M = fmaxf(M, part[3][lane][0]);
            float Lt = 0.f;
            float o[16];
#pragma unroll
            for (int d = 0; d < 16; d++) o[d] = 0.f;
#pragma unroll
            for (int w = 0; w < 4; w++) {
                const float* qq = part[w][lane];
                float r = __expf(qq[0] - M);
                Lt += qq[1] * r;
#pragma unroll
                for (int d = 0; d < 16; d++) o[d] += qq[2 + d] * r;
            }
            if (valid) {
                float il = 1.0f / Lt;
                float* op = F + (size_t)(b * NTOK + nq) * DE + h * HD;
#pragma unroll
                for (int d4 = 0; d4 < 4; d4++)
                    ((float4*)op)[d4] = make_float4(o[4*d4]*il, o[4*d4+1]*il,
                                                    o[4*d4+2]*il, o[4*d4+3]*il);
            }
        }
        __syncthreads();
    }
}

// ---- kernel 4: proj (coalesced WfT) + bias + residual, 8 tokens/block ----
__global__ __launch_bounds__(256) void k_proj(
    const float* __restrict__ x, const float* __restrict__ F,
    const float* __restrict__ WfT, const float* __restrict__ bf,
    float* __restrict__ out) {
    __shared__ float fr[8][DE];
    int t0 = blockIdx.x * 8;
    int tid = threadIdx.x;
    ((float4*)fr)[tid] = ((const float4*)(F + (size_t)t0 * DE))[tid];
    __syncthreads();
    float acc0[8], acc1[8];
    float b0 = bf[tid], b1 = bf[tid + 256];
#pragma unroll
    for (int tk = 0; tk < 8; tk++) { acc0[tk] = b0; acc1[tk] = b1; }
#pragma unroll 4
    for (int k = 0; k < DE; k++) {
        float w0 = WfT[(size_t)k * DF + tid];
        float w1 = WfT[(size_t)k * DF + tid + 256];
#pragma unroll
        for (int tk = 0; tk < 8; tk++) {
            float fv = fr[tk][k];
            acc0[tk] += fv * w0;
            acc1[tk] += fv * w1;
        }
    }
#pragma unroll
    for (int tk = 0; tk < 8; tk++) {
        size_t rb = (size_t)(t0 + tk) * DF;
        out[rb + tid]       = x[rb + tid]       + acc0[tk];
        out[rb + tid + 256] = x[rb + tid + 256] + acc1[tk];
    }
}

extern "C" void kernel_launch(void* const* d_in, const int* in_sizes, int n_in,
                              void* d_out, int out_size, void* d_ws, size_t ws_size,
                              hipStream_t stream) {
    (void)in_sizes; (void)n_in; (void)out_size; (void)ws_size;
    const float* x     = (const float*)d_in[0];
    const float* fp    = (const float*)d_in[1];
    const float* lnw   = (const float*)d_in[2];
    const float* lnb   = (const float*)d_in[3];
    const float* alpha = (const float*)d_in[4];
    const float* Wg1   = (const float*)d_in[5];
    const float* bg1   = (const float*)d_in[6];
    const float* Wg2   = (const float*)d_in[7];
    const float* bg2   = (const float*)d_in[8];
    const float* Wq    = (const float*)d_in[9];
    const float* Wk    = (const float*)d_in[10];
    const float* Wv    = (const float*)d_in[11];
    const float* temp  = (const float*)d_in[12];
    const float* Wf    = (const float*)d_in[13];
    const float* bf    = (const float*)d_in[14];
    float* out = (float*)d_out;

    char* ws = (char*)d_ws;
    unsigned* cnt = (unsigned*)ws;                     // 1 KB
    unsigned* lst = (unsigned*)(ws + 1024);            // 32 KB
    float* fg  = (float*)(ws + 65536);                 // 512 KB: [B*NTOK][64]
    float* Qb  = fg + (size_t)B * NTOK * S;            // 1 MB each
    float* Kb  = Qb + (size_t)B * NTOK * DE;
    float* Vb  = Kb + (size_t)B * NTOK * DE;
    float* Fb  = Vb + (size_t)B * NTOK * DE;
    float* WfT = Fb + (size_t)B * NTOK * DE;           // 256 KB
    float* WqT = WfT + (size_t)DE * DF;                // 256 KB each
    float* WkT = WqT + (size_t)E * S * DE;
    float* WvT = WkT + (size_t)E * S * DE;

    hipLaunchKernelGGL(k_prep, dim3(200), dim3(256), 0, stream,
                       Wq, Wk, Wv, Wf, fp, x, lnw, lnb, alpha, Wg1, bg1, Wg2, bg2,
                       WfT, WqT, WkT, WvT, cnt, lst, fg);
    hipLaunchKernelGGL(k_qkv, dim3(B * E * 16), dim3(256), 0, stream,
                       fg, WqT, WkT, WvT, cnt, lst, Qb, Kb, Vb);
    hipLaunchKernelGGL(k_attn, dim3(B * E * H * QT), dim3(256), 0, stream,
                       Qb, Kb, Vb, cnt, lst, temp, Fb);
    hipLaunchKernelGGL(k_proj, dim3(B * NTOK / 8), dim3(256), 0, stream,
                       x, Fb, WfT, bf, out);
}